// Round 10
// baseline (534.340 us; speedup 1.0000x reference)
//
#include <hip/hip_runtime.h>

#define H_ 160
#define W_ 160
#define HW 25600
#define L_ 51200
#define DM 128
#define DI 512
#define DS 256
#define NH 16
#define HD 32
#define CONVD 1024
#define DIP 1552
#define NCH 800      // number of chunks
#define NCH2 400     // chunks per half
#define KSL 64       // K-slices for k_carry
#define CPS 7        // chunks per K-slice (ceil(400/64) -> 7, tail slices idle)
#define EPSV 1e-5f

typedef __attribute__((ext_vector_type(8))) short bf16x8;
typedef __attribute__((ext_vector_type(8))) unsigned short us8;
typedef __attribute__((ext_vector_type(4))) unsigned short us4;
typedef __attribute__((ext_vector_type(4))) float f32x4;
#define MFMA16(a,b,c) __builtin_amdgcn_mfma_f32_16x16x32_bf16(a,b,c,0,0,0)

__device__ __forceinline__ float b2f(unsigned short u){
  union{unsigned int i; float f;} v; v.i = ((unsigned int)u) << 16; return v.f;
}
__device__ __forceinline__ unsigned short f2b(float f){
  union{unsigned int i; float f;} v; v.f = f;
  unsigned int r = v.i + 0x7fffu + ((v.i >> 16) & 1u);
  return (unsigned short)(r >> 16);
}

// ---------------------------------------------------------------- K0: coef
__global__ void k_coef(const float* __restrict__ opw, const float* __restrict__ nw,
                       float* __restrict__ coef){
  int i = blockIdx.x * blockDim.x + threadIdx.x;
  if (i >= DI) return;
  float s = 0.f;
  for (int j = 0; j < DM; ++j) s += opw[j * DI + i];
  coef[i] = (s / (float)DM) * nw[i];
}

// ---------------------------------------------------------------- K0b: rank-4 table q[j] = (w.fw0, w.fw1, w.fw2, w.fb)
__global__ __launch_bounds__(256) void k_qtab(const float* __restrict__ ipw,
    const float* __restrict__ fw, const float* __restrict__ fb, float* __restrict__ q){
  int j = blockIdx.x * 256 + threadIdx.x;
  if (j >= DIP) return;
  const float* wr = ipw + (size_t)j * DM;
  float s0 = 0.f, s1 = 0.f, s2 = 0.f, sb = 0.f;
  for (int k = 0; k < DM; ++k){
    float w = wr[k];
    s0 += w * fw[k*3+0]; s1 += w * fw[k*3+1]; s2 += w * fw[k*3+2]; sb += w * fb[k];
  }
  reinterpret_cast<float4*>(q)[j] = make_float4(s0, s1, s2, sb);
}

// ---------------------------------------------------------------- helpers
__device__ __forceinline__ void xrow(const float* __restrict__ x, int l, float* o){
  int i, j;
  if (l < HW){ i = l / W_; j = l % W_; }
  else { int l2 = l - HW; i = (H_ - 1) - l2 / W_; j = (W_ - 1) - l2 % W_; }
  int p = i * W_ + j;
  o[0] = x[p]; o[1] = x[HW + p]; o[2] = x[2*HW + p];
}

// ---------------------------------------------------------------- K2: fused fc0 + in_proj + conv + silu + dt (rank-4)
// 3200 blocks: (bid>>1) picks 32-row span, (bid&1) picks channel half. z distributed over all blocks.
__global__ __launch_bounds__(256) void k_fused(const float* __restrict__ x,
    const float* __restrict__ q, const float* __restrict__ cw, const float* __restrict__ cb,
    const float* __restrict__ dt_bias,
    unsigned short* __restrict__ g, unsigned short* __restrict__ xbc, float* __restrict__ dtb){
  int bid = blockIdx.x;
  int r0 = (bid >> 1) * 32;
  int chalf = bid & 1;
  int tid = threadIdx.x;
  // --- xBC: conv + silu. 8 l4-groups x 64 ch-slots (512 channels)
  {
    int c8 = (tid & 63) | (chalf << 6);    // 0..127 channel-group of 8
    int lg = tid >> 6;                     // 0..3
    const float4* qv8 = reinterpret_cast<const float4*>(q) + DI + c8 * 8;
    const float4* wv8 = reinterpret_cast<const float4*>(cw) + c8 * 8;
    const float4* cb2 = reinterpret_cast<const float4*>(cb) + c8 * 2;
    float4 bias0 = cb2[0], bias1 = cb2[1];
    float biasv[8] = {bias0.x,bias0.y,bias0.z,bias0.w,bias1.x,bias1.y,bias1.z,bias1.w};
    for (int it = 0; it < 2; ++it){
      int lbase = r0 + (it * 4 + lg) * 4;       // output rows lbase..lbase+3
      float xv[7][3], vf[7];
      #pragma unroll
      for (int k = 0; k < 7; ++k){
        int l = lbase - 3 + k;
        if (l >= 0){ xrow(x, l, xv[k]); vf[k] = 1.f; }
        else { xv[k][0] = xv[k][1] = xv[k][2] = 0.f; vf[k] = 0.f; }
      }
      unsigned int ow[4][4];
      #pragma unroll
      for (int e = 0; e < 8; ++e){
        float4 qv = qv8[e];
        float raw[7];
        #pragma unroll
        for (int k = 0; k < 7; ++k)
          raw[k] = vf[k]*qv.w + xv[k][0]*qv.x + xv[k][1]*qv.y + xv[k][2]*qv.z;
        float4 wv = wv8[e];
        float bias = biasv[e];
        #pragma unroll
        for (int rr = 0; rr < 4; ++rr){
          float acc = bias + raw[rr]*wv.x + raw[rr+1]*wv.y + raw[rr+2]*wv.z + raw[rr+3]*wv.w;
          float s = acc / (1.f + __expf(-acc));
          unsigned int b = f2b(s);
          if (e & 1) ow[rr][e >> 1] |= b << 16;
          else       ow[rr][e >> 1] = b;
        }
      }
      #pragma unroll
      for (int rr = 0; rr < 4; ++rr){
        uint4 o; o.x = ow[rr][0]; o.y = ow[rr][1]; o.z = ow[rr][2]; o.w = ow[rr][3];
        *reinterpret_cast<uint4*>(xbc + (size_t)(lbase + rr) * CONVD + c8 * 8) = o;
      }
    }
  }
  // --- z gate: silu, 8 rows x 512 cols per block (distributed over all 3200 blocks)
  {
    int c8g = tid & 63;
    const float4* qv8 = reinterpret_cast<const float4*>(q) + c8g * 8;
    for (int it = 0; it < 2; ++it){
      int row = it * 4 + (tid >> 6);
      int l = HW + bid * 8 + row;
      float xv[3]; xrow(x, l, xv);
      unsigned int ow[4];
      #pragma unroll
      for (int e = 0; e < 8; ++e){
        float4 qv = qv8[e];
        float raw = qv.w + xv[0]*qv.x + xv[1]*qv.y + xv[2]*qv.z;
        float s = raw / (1.f + __expf(-raw));
        unsigned int b = f2b(s);
        if (e & 1) ow[e >> 1] |= b << 16;
        else       ow[e >> 1] = b;
      }
      uint4 o; o.x = ow[0]; o.y = ow[1]; o.z = ow[2]; o.w = ow[3];
      *reinterpret_cast<uint4*>(g + (size_t)(bid * 8 + row) * DI + c8g * 8) = o;
    }
  }
  // --- dt: softplus, f32. 16 rows x 16 h per block
  {
    int row = tid >> 4, h = tid & 15;
    int l = r0 + chalf * 16 + row;
    float xv[3]; xrow(x, l, xv);
    float4 qv = reinterpret_cast<const float4*>(q)[DI + CONVD + h];
    float raw = qv.w + xv[0]*qv.x + xv[1]*qv.y + xv[2]*qv.z + dt_bias[h];
    float sp = (raw > 20.f) ? raw : log1pf(__expf(raw));
    dtb[(size_t)l * NH + h] = sp;
  }
}

// ---------------------------------------------------------------- K3a: per-chunk sums of dt*A (first half)
__global__ void k_csum(const float* __restrict__ dtb, const float* __restrict__ A_log,
                       float* __restrict__ Scs){
  int idx = blockIdx.x * 256 + threadIdx.x;   // 6400 = 400 c x 16 h
  if (idx >= NCH2 * NH) return;
  int c = idx >> 4, h = idx & 15;
  float Ah = -__expf(A_log[h]);
  float s = 0.f;
  const float* p = dtb + (size_t)c * 64 * NH + h;
  for (int t = 0; t < 64; ++t) s += p[t * NH];
  Scs[idx] = s * Ah;
}

// ---------------------------------------------------------------- K3b: exclusive chunk prefix + total (first half)
__global__ __launch_bounds__(256) void k_cpre(const float* __restrict__ Scs,
    float* __restrict__ chunkpre, float* __restrict__ Ttot){
  __shared__ float segs[256];   // [seg][h]
  int tid = threadIdx.x;
  int h = tid & 15, seg = tid >> 4;
  int c0 = seg * 25;
  float v[25];
  float s = 0.f;
  #pragma unroll
  for (int j = 0; j < 25; ++j){ v[j] = Scs[(c0 + j) * NH + h]; s += v[j]; }
  segs[seg * 16 + h] = s;
  __syncthreads();
  float excl = 0.f;
  for (int s2 = 0; s2 < seg; ++s2) excl += segs[s2 * 16 + h];
  float run = excl;
  #pragma unroll
  for (int j = 0; j < 25; ++j){ chunkpre[(c0 + j) * NH + h] = run; run += v[j]; }
  if (seg == 15) Ttot[h] = run;
}

// ---------------------------------------------------------------- K3c: first-half carry, 4 heads per block
// carry[h,p,n] = sum_l exp(Ttot - pre_c - localcs(l)) * dt*x[l,h,p] * B[l,n]
__global__ __launch_bounds__(256) void k_carry(const unsigned short* __restrict__ xbc,
    const float* __restrict__ dtb, const float* __restrict__ A_log,
    const float* __restrict__ chunkpre, const float* __restrict__ Ttot,
    float* __restrict__ part){
  __shared__ char U[50176];      // Bs 32KB + xwT4 16KB + wcs 1KB
  unsigned short* Bs = (unsigned short*)U;
  char* xwT4 = U + 32768;        // [4][32][64] bf16 swizzled
  float* wcs = (float*)(U + 49152);   // [4][64]
  int ks = blockIdx.x >> 2, hg = blockIdx.x & 3;
  int hbase = hg * 4;
  int tid = threadIdx.x, lane = tid & 63, wv = tid >> 6;
  int kg = lane >> 4, l15 = lane & 15;
  int c0 = ks * CPS, cend = min(c0 + CPS, NCH2);
  float Ahw = -__expf(A_log[hbase + wv]);     // wave-uniform
  float Ttw = Ttot[hbase + wv];
  f32x4 sacc[4][2][4];
  #pragma unroll
  for (int hh = 0; hh < 4; ++hh)
    #pragma unroll
    for (int mt = 0; mt < 2; ++mt)
      #pragma unroll
      for (int nt = 0; nt < 4; ++nt) sacc[hh][mt][nt] = (f32x4){0.f,0.f,0.f,0.f};
  for (int c = c0; c < cend; ++c){
    int l0 = c * 64;
    __syncthreads();                       // prev chunk's LDS reads done
    #pragma unroll
    for (int it = 0; it < 8; ++it){
      int r = (tid >> 5) + 8 * it, c8 = tid & 31;
      uint4 v = *reinterpret_cast<const uint4*>(xbc + (size_t)(l0 + r) * CONVD + DI + c8 * 8);
      *reinterpret_cast<uint4*>((char*)Bs + ((r * 512 + c8 * 16) ^ ((r & 7) << 4))) = v;
    }
    {                                      // per-wave 64-lane scan for its own head
      float d = dtb[(size_t)(l0 + lane) * NH + hbase + wv] * Ahw;
      #pragma unroll
      for (int off = 1; off < 64; off <<= 1){
        float o = __shfl_up(d, off, 64);
        if (lane >= off) d += o;
      }
      wcs[wv * 64 + lane] = __expf(Ttw - chunkpre[c * NH + hbase + wv] - d);
    }
    __syncthreads();                       // Bs + wcs ready
    // B^T fragments (shared across 4 heads)
    bf16x8 bst[8];
    #pragma unroll
    for (int nt = 0; nt < 4; ++nt)
      #pragma unroll
      for (int s = 0; s < 2; ++s){
        int n = wv * 64 + nt * 16 + l15;
        int tb = s * 32 + kg * 8;
        bf16x8 f;
        #pragma unroll
        for (int e = 0; e < 8; ++e){
          int t = tb + e;
          f[e] = *reinterpret_cast<const short*>((char*)Bs + ((t * 512 + n * 2) ^ ((t & 7) << 4)));
        }
        bst[nt * 2 + s] = f;
      }
    // xwT for all 4 heads
    #pragma unroll
    for (int hh = 0; hh < 4; ++hh){
      int t = lane, pb = wv;
      float w = wcs[hh * 64 + t] * dtb[(size_t)(l0 + t) * NH + hbase + hh];
      us8 x8 = *reinterpret_cast<const us8*>(xbc + (size_t)(l0 + t) * CONVD + (hbase + hh) * HD + pb * 8);
      #pragma unroll
      for (int e = 0; e < 8; ++e){
        int pp = pb * 8 + e;
        *reinterpret_cast<unsigned short*>(xwT4 + hh * 4096 + ((pp * 128 + t * 2) ^ ((pp & 7) << 4))) = f2b(b2f(x8[e]) * w);
      }
    }
    __syncthreads();                       // xwT ready
    #pragma unroll
    for (int s = 0; s < 2; ++s)
      #pragma unroll
      for (int hh = 0; hh < 4; ++hh)
        #pragma unroll
        for (int mt = 0; mt < 2; ++mt){
          int pr = mt * 16 + l15;
          bf16x8 a = *reinterpret_cast<const bf16x8*>(xwT4 + hh * 4096 + ((pr * 128 + (s*32 + kg*8) * 2) ^ ((pr & 7) << 4)));
          #pragma unroll
          for (int nt = 0; nt < 4; ++nt) sacc[hh][mt][nt] = MFMA16(a, bst[nt*2 + s], sacc[hh][mt][nt]);
        }
  }
  #pragma unroll
  for (int hh = 0; hh < 4; ++hh){
    float* pb2 = part + ((size_t)(ks * NH + hbase + hh)) * HD * DS;
    #pragma unroll
    for (int mt = 0; mt < 2; ++mt)
      #pragma unroll
      for (int nt = 0; nt < 4; ++nt)
        #pragma unroll
        for (int r = 0; r < 4; ++r)
          pb2[(mt * 16 + kg * 4 + r) * DS + wv * 64 + nt * 16 + l15] = sacc[hh][mt][nt][r];
  }
}

// ---------------------------------------------------------------- K3d: reduce K-slice partials -> carry
__global__ __launch_bounds__(256) void k_carryred(const float* __restrict__ part,
                                                  float* __restrict__ carry){
  int idx = blockIdx.x * 256 + threadIdx.x;  // 131072
  float s = 0.f;
  #pragma unroll 8
  for (int ks = 0; ks < KSL; ++ks) s += part[(size_t)ks * 131072 + idx];
  carry[idx] = s;
}

// ---------------------------------------------------------------- K4: per-chunk SSD core (second half), 16 heads/block
__global__ __launch_bounds__(256) void k_chunk(const unsigned short* __restrict__ xbc,
    const float* __restrict__ dtb, const float* __restrict__ A_log,
    unsigned short* __restrict__ states, float* __restrict__ atot,
    float* __restrict__ ecs, unsigned short* __restrict__ ydiag){
  __shared__ char U[65536];
  __shared__ float dts[1024];        // [t*16+h]
  __shared__ float Acs[1024];        // [h*64+t]
  unsigned short* Bs = (unsigned short*)U;
  unsigned short* Cs = (unsigned short*)(U + 32768);
  char* Mb  = U;                                   // [64][64] bf16 swizzled (8KB)
  char* xdT = U + 8192;                            // [32][64] bf16 swizzled (4KB)
  char* xwT = U + 12288;                           // [32][64] bf16 swizzled (4KB)
  unsigned short* stageS = (unsigned short*)(U + 16384);   // [32][264] bf16
  unsigned short* stageY = (unsigned short*)(U + 33280);   // [64][40] bf16
  int cl = blockIdx.x;
  int c = NCH2 + cl, l0 = c * 64;
  int tid = threadIdx.x, lane = tid & 63, wv = tid >> 6;
  int kg = lane >> 4, l15 = lane & 15;

  for (int i = tid; i < 1024; i += 256) dts[i] = dtb[(size_t)l0 * NH + i];
  #pragma unroll
  for (int it = 0; it < 8; ++it){
    int r = (tid >> 5) + 8 * it, c8 = tid & 31;
    uint4 v = *reinterpret_cast<const uint4*>(xbc + (size_t)(l0 + r) * CONVD + DI + c8 * 8);
    *reinterpret_cast<uint4*>((char*)Bs + ((r * 512 + c8 * 16) ^ ((r & 7) << 4))) = v;
    uint4 v2 = *reinterpret_cast<const uint4*>(xbc + (size_t)(l0 + r) * CONVD + DI + DS + c8 * 8);
    *reinterpret_cast<uint4*>((char*)Cs + ((r * 512 + c8 * 16) ^ ((r & 7) << 4))) = v2;
  }
  __syncthreads();
  if (tid < 16){
    int h = tid; float Ah = -__expf(A_log[h]); float s = 0.f;
    for (int t = 0; t < 64; ++t){ s += dts[t*16 + h] * Ah; Acs[h*64 + t] = s; }
    atot[c * NH + h] = __expf(s);
  }
  bf16x8 bst[8];     // [nt*2 + s]
  #pragma unroll
  for (int nt = 0; nt < 4; ++nt)
    #pragma unroll
    for (int s = 0; s < 2; ++s){
      int n = wv * 64 + nt * 16 + l15;
      int tb = s * 32 + kg * 8;
      bf16x8 f;
      #pragma unroll
      for (int e = 0; e < 8; ++e){
        int t = tb + e;
        f[e] = *reinterpret_cast<const short*>((char*)Bs + ((t * 512 + n * 2) ^ ((t & 7) << 4)));
      }
      bst[nt * 2 + s] = f;
    }
  f32x4 Gacc[4];
  {
    #pragma unroll
    for (int st = 0; st < 4; ++st) Gacc[st] = (f32x4){0.f,0.f,0.f,0.f};
    int trow = wv * 16 + l15;
    for (int ks = 0; ks < 8; ++ks){
      bf16x8 a = *reinterpret_cast<const bf16x8*>((char*)Cs + ((trow * 512 + (ks*32 + kg*8) * 2) ^ ((trow & 7) << 4)));
      #pragma unroll
      for (int st = 0; st < 4; ++st){
        int srow = st * 16 + l15;
        bf16x8 b = *reinterpret_cast<const bf16x8*>((char*)Bs + ((srow * 512 + (ks*32 + kg*8) * 2) ^ ((srow & 7) << 4)));
        Gacc[st] = MFMA16(a, b, Gacc[st]);
      }
    }
  }
  __syncthreads();     // Bs/Cs dead; Acs ready
  for (int h = 0; h < NH; ++h){
    float alast = Acs[h*64 + 63];
    {
      int t = tid & 63, pb = tid >> 6;
      float dtv = dts[t*16 + h];
      float dec = __expf(alast - Acs[h*64 + t]);
      us8 x8 = *reinterpret_cast<const us8*>(xbc + (size_t)(l0 + t) * CONVD + h * HD + pb * 8);
      #pragma unroll
      for (int e = 0; e < 8; ++e){
        int pp = pb * 8 + e;
        float v = b2f(x8[e]) * dtv;
        *reinterpret_cast<unsigned short*>(xdT + ((pp * 128 + t * 2) ^ ((pp & 7) << 4))) = f2b(v);
        *reinterpret_cast<unsigned short*>(xwT + ((pp * 128 + t * 2) ^ ((pp & 7) << 4))) = f2b(v * dec);
      }
    }
    {
      #pragma unroll
      for (int st = 0; st < 4; ++st)
        #pragma unroll
        for (int r = 0; r < 4; ++r){
          int t = wv * 16 + kg * 4 + r, s2 = st * 16 + l15;
          float m = (s2 <= t) ? Gacc[st][r] * __expf(Acs[h*64 + t] - Acs[h*64 + s2]) : 0.f;
          *reinterpret_cast<unsigned short*>(Mb + ((t * 128 + s2 * 2) ^ ((t & 7) << 4))) = f2b(m);
        }
      if (tid < 64) ecs[((size_t)cl * NH + h) * 64 + tid] = __expf(Acs[h*64 + tid]);
    }
    __syncthreads();
    {
      f32x4 sacc[2][4];
      #pragma unroll
      for (int mt = 0; mt < 2; ++mt)
        #pragma unroll
        for (int nt = 0; nt < 4; ++nt) sacc[mt][nt] = (f32x4){0.f,0.f,0.f,0.f};
      #pragma unroll
      for (int s = 0; s < 2; ++s)
        #pragma unroll
        for (int mt = 0; mt < 2; ++mt){
          int pr = mt * 16 + l15;
          bf16x8 a = *reinterpret_cast<const bf16x8*>(xwT + ((pr * 128 + (s*32 + kg*8) * 2) ^ ((pr & 7) << 4)));
          #pragma unroll
          for (int nt = 0; nt < 4; ++nt) sacc[mt][nt] = MFMA16(a, bst[nt*2 + s], sacc[mt][nt]);
        }
      #pragma unroll
      for (int mt = 0; mt < 2; ++mt)
        #pragma unroll
        for (int nt = 0; nt < 4; ++nt)
          #pragma unroll
          for (int r = 0; r < 4; ++r){
            int pp = mt * 16 + kg * 4 + r, n = wv * 64 + nt * 16 + l15;
            stageS[pp * 264 + n] = f2b(sacc[mt][nt][r]);
          }
    }
    {
      f32x4 yacc[2];
      yacc[0] = (f32x4){0.f,0.f,0.f,0.f}; yacc[1] = (f32x4){0.f,0.f,0.f,0.f};
      int trow = wv * 16 + l15;
      #pragma unroll
      for (int s = 0; s < 2; ++s){
        bf16x8 a = *reinterpret_cast<const bf16x8*>(Mb + ((trow * 128 + (s*32 + kg*8) * 2) ^ ((trow & 7) << 4)));
        #pragma unroll
        for (int pt = 0; pt < 2; ++pt){
          int pr = pt * 16 + l15;
          bf16x8 b = *reinterpret_cast<const bf16x8*>(xdT + ((pr * 128 + (s*32 + kg*8) * 2) ^ ((pr & 7) << 4)));
          yacc[pt] = MFMA16(a, b, yacc[pt]);
        }
      }
      #pragma unroll
      for (int pt = 0; pt < 2; ++pt)
        #pragma unroll
        for (int r = 0; r < 4; ++r){
          int t = wv * 16 + kg * 4 + r, pp = pt * 16 + l15;
          stageY[t * 40 + pp] = f2b(yacc[pt][r]);
        }
    }
    __syncthreads();
    {
      int row = tid >> 3, seg = tid & 7;
      const unsigned short* sp = stageS + row * 264 + seg * 32;
      unsigned short* gp = states + (((size_t)cl * NH + h) * HD + row) * DS + seg * 32;
      #pragma unroll
      for (int k = 0; k < 4; ++k)
        *reinterpret_cast<uint4*>(gp + k * 8) = *reinterpret_cast<const uint4*>(sp + k * 8);
      {
        int rw = tid >> 2, quad = tid & 3;
        *reinterpret_cast<uint4*>(ydiag + (size_t)(l0 - HW + rw) * DI + h * HD + quad * 8)
          = *reinterpret_cast<const uint4*>(stageY + rw * 40 + quad * 8);
      }
    }
    __syncthreads();
  }
}

// ---------------------------------------------------------------- K5b: in-place prefix over second-half states
__global__ __launch_bounds__(256) void k_scan2(unsigned short* __restrict__ states,
    const float* __restrict__ atot, const float* __restrict__ carry){
  __shared__ float sat[NCH2];
  int idx = blockIdx.x * 256 + threadIdx.x;
  int h = idx >> 13;
  for (int c = threadIdx.x; c < NCH2; c += 256) sat[c] = atot[(NCH2 + c) * NH + h];
  __syncthreads();
  float cr = carry[idx];
  unsigned short* p = states + idx;
  for (int c = 0; c < NCH2; ++c){
    float s = b2f(*p);
    *p = f2b(cr);
    cr = sat[c] * cr + s;
    p += 131072;
  }
}

// ---------------------------------------------------------------- K6: Y_off + skip + gate + sumsq (MFMA, LDS-staged)
__global__ __launch_bounds__(256) void k_yoff(const unsigned short* __restrict__ xbc,
    const unsigned short* __restrict__ states, const float* __restrict__ ecs,
    const float* __restrict__ Dv, unsigned short* __restrict__ y,
    const unsigned short* __restrict__ g, float* __restrict__ rms){
  __shared__ unsigned short stage[64 * 520];
  __shared__ float ecs_s[1024];
  int c2 = blockIdx.x;
  int c = c2 + NCH2, l0 = c * 64;
  int tid = threadIdx.x, lane = tid & 63, wv = tid >> 6;
  int kg = lane >> 4, l15 = lane & 15;
  for (int i = tid; i < 1024; i += 256) ecs_s[i] = ecs[(size_t)c2 * 1024 + i];
  bf16x8 aC[8];
  int trow = wv * 16 + l15;
  #pragma unroll
  for (int ks = 0; ks < 8; ++ks)
    aC[ks] = *reinterpret_cast<const bf16x8*>(xbc + (size_t)(l0 + trow) * CONVD + DI + DS + ks * 32 + kg * 8);
  __syncthreads();
  for (int h = 0; h < NH; ++h){
    f32x4 acc[2];
    acc[0] = (f32x4){0.f,0.f,0.f,0.f}; acc[1] = (f32x4){0.f,0.f,0.f,0.f};
    const unsigned short* sb = states + ((size_t)c2 * NH + h) * HD * DS;
    #pragma unroll
    for (int ks = 0; ks < 8; ++ks)
      #pragma unroll
      for (int pt = 0; pt < 2; ++pt){
        bf16x8 b = *reinterpret_cast<const bf16x8*>(sb + (pt * 16 + l15) * DS + ks * 32 + kg * 8);
        acc[pt] = MFMA16(aC[ks], b, acc[pt]);
      }
    float Dh = Dv[h];
    #pragma unroll
    for (int pt = 0; pt < 2; ++pt)
      #pragma unroll
      for (int r = 0; r < 4; ++r){
        int t = wv * 16 + kg * 4 + r, pp = pt * 16 + l15;
        float xh = b2f(xbc[(size_t)(l0 + t) * CONVD + h * HD + pp]);
        stage[t * 520 + h * HD + pp] = f2b(ecs_s[h*64 + t] * acc[pt][r] + Dh * xh);
      }
  }
  __syncthreads();
  int row = tid >> 2, quad = tid & 3;
  const unsigned short* sr = stage + row * 520 + quad * 128;
  size_t obase = (size_t)(c2 * 64 + row) * DI + quad * 128;
  float ss = 0.f;
  #pragma unroll
  for (int k = 0; k < 16; ++k){
    uint4 sv = *reinterpret_cast<const uint4*>(sr + k * 8);
    uint4 yv = *reinterpret_cast<const uint4*>(y + obase + k * 8);
    uint4 gv = *reinterpret_cast<const uint4*>(g + obase + k * 8);
    unsigned int ow[4];
    const unsigned int* svp = (const unsigned int*)&sv;
    const unsigned int* yvp = (const unsigned int*)&yv;
    const unsigned int* gvp = (const unsigned int*)&gv;
    #pragma unroll
    for (int e = 0; e < 4; ++e){
      float v0 = b2f((unsigned short)(svp[e] & 0xffff)) + b2f((unsigned short)(yvp[e] & 0xffff));
      float v1 = b2f((unsigned short)(svp[e] >> 16)) + b2f((unsigned short)(yvp[e] >> 16));
      float y0 = v0 * b2f((unsigned short)(gvp[e] & 0xffff));
      float y1 = v1 * b2f((unsigned short)(gvp[e] >> 16));
      ss += y0 * y0 + y1 * y1;
      ow[e] = (unsigned int)f2b(y0) | ((unsigned int)f2b(y1) << 16);
    }
    uint4 o; o.x = ow[0]; o.y = ow[1]; o.z = ow[2]; o.w = ow[3];
    *reinterpret_cast<uint4*>(y + obase + k * 8) = o;
  }
  ss += __shfl_xor(ss, 1, 64);
  ss += __shfl_xor(ss, 2, 64);
  if (quad == 0) rms[c2 * 64 + row] = rsqrtf(ss / (float)DI + EPSV);
}

// ---------------------------------------------------------------- K7: half[l] = rms * (y . coef)
__global__ __launch_bounds__(256) void k_half(const unsigned short* __restrict__ yg,
    const float* __restrict__ rms, const float* __restrict__ coef,
    float* __restrict__ half_out){
  int wave = threadIdx.x >> 6, lane = threadIdx.x & 63;
  int row = blockIdx.x * 4 + wave;
  if (row >= HW) return;
  const unsigned short* yr = yg + (size_t)row * DI;
  float acc = 0.f;
  for (int i = lane; i < DI; i += 64) acc += b2f(yr[i]) * coef[i];
  #pragma unroll
  for (int off = 32; off; off >>= 1) acc += __shfl_down(acc, off, 64);
  if (lane == 0) half_out[row] = acc * rms[row];
}

// ---------------------------------------------------------------- K8: final fc1
__global__ __launch_bounds__(256) void k_fc1(const float* __restrict__ half_in,
    const float* __restrict__ w, const float* __restrict__ b, float* __restrict__ out){
  int k = blockIdx.x;
  const float* wr = w + (size_t)k * HW;
  float acc = 0.f;
  for (int i = threadIdx.x; i < HW; i += 256) acc += half_in[i] * wr[i];
  __shared__ float red[256];
  red[threadIdx.x] = acc;
  __syncthreads();
  for (int s = 128; s; s >>= 1){
    if (threadIdx.x < s) red[threadIdx.x] += red[threadIdx.x + s];
    __syncthreads();
  }
  if (threadIdx.x == 0) out[k] = red[0] + b[k];
}

// ---------------------------------------------------------------- launch
extern "C" void kernel_launch(void* const* d_in, const int* in_sizes, int n_in,
                              void* d_out, int out_size, void* d_ws, size_t ws_size,
                              hipStream_t stream){
  const float* x      = (const float*)d_in[0];
  const float* fc0_w  = (const float*)d_in[1];
  const float* fc0_b  = (const float*)d_in[2];
  const float* ipw    = (const float*)d_in[3];
  const float* conv_w = (const float*)d_in[4];
  const float* conv_b = (const float*)d_in[5];
  const float* dt_bias= (const float*)d_in[6];
  const float* A_log  = (const float*)d_in[7];
  const float* Dv     = (const float*)d_in[8];
  const float* norm_w = (const float*)d_in[9];
  const float* opw    = (const float*)d_in[10];
  const float* fc1_w  = (const float*)d_in[11];
  const float* fc1_b  = (const float*)d_in[12];
  float* out = (float*)d_out;

  char* ws = (char*)d_ws;
  size_t off = 0;
  float* dtb          = (float*)(ws + off);           off += (size_t)L_ * NH * 4;          // 3.3 MB
  unsigned short* stx = (unsigned short*)(ws + off);  off += (size_t)L_ * CONVD * 2;       // 104.9 MB (carry partials, then 400-chunk states)
  unsigned short* xbc = (unsigned short*)(ws + off);  off += (size_t)L_ * CONVD * 2;       // 104.9 MB
  unsigned short* g   = (unsigned short*)(ws + off);  off += (size_t)HW * DI * 2;          // 26.2 MB
  unsigned short* yd  = (unsigned short*)(ws + off);  off += (size_t)HW * DI * 2;          // 26.2 MB
  float* atot         = (float*)(ws + off);           off += (size_t)NCH * NH * 4;
  float* ecs          = (float*)(ws + off);           off += (size_t)NCH2 * NH * 64 * 4;
  float* rms          = (float*)(ws + off);           off += (size_t)HW * 4;
  float* half_buf     = (float*)(ws + off);           off += (size_t)HW * 4;
  float* coef         = (float*)(ws + off);           off += (size_t)DI * 4;
  float* carry        = (float*)(ws + off);           off += (size_t)131072 * 4;
  float* qtab         = (float*)(ws + off);           off += (size_t)DIP * 4 * 4;
  float* Scs          = (float*)(ws + off);           off += (size_t)NCH2 * NH * 4;
  float* chunkpre     = (float*)(ws + off);           off += (size_t)NCH2 * NH * 4;
  float* Ttot         = (float*)(ws + off);           off += (size_t)NH * 4;
  float* part         = (float*)stx;                  // alias: dead before k_chunk writes stx

  if (ws_size < off) return;   // diagnostic guard

  k_coef    <<<2, 256, 0, stream>>>(opw, norm_w, coef);
  k_qtab    <<<(DIP + 255) / 256, 256, 0, stream>>>(ipw, fc0_w, fc0_b, qtab);
  k_fused   <<<L_ / 16, 256, 0, stream>>>(x, qtab, conv_w, conv_b, dt_bias, g, xbc, dtb);
  k_csum    <<<25, 256, 0, stream>>>(dtb, A_log, Scs);
  k_cpre    <<<1, 256, 0, stream>>>(Scs, chunkpre, Ttot);
  k_carry   <<<KSL * 4, 256, 0, stream>>>(xbc, dtb, A_log, chunkpre, Ttot, part);
  k_carryred<<<512, 256, 0, stream>>>(part, carry);
  k_chunk   <<<NCH2, 256, 0, stream>>>(xbc, dtb, A_log, stx, atot, ecs, yd);
  k_scan2   <<<512, 256, 0, stream>>>(stx, atot, carry);
  k_yoff    <<<NCH2, 256, 0, stream>>>(xbc, stx, ecs, Dv, yd, g, rms);
  k_half    <<<HW / 4, 256, 0, stream>>>(yd, rms, coef, half_buf);
  k_fc1     <<<DM, 256, 0, stream>>>(half_buf, fc1_w, fc1_b, out);
}

// Round 11
// 479.742 us; speedup vs baseline: 1.1138x; 1.1138x over previous
//
#include <hip/hip_runtime.h>

#define H_ 160
#define W_ 160
#define HW 25600
#define L_ 51200
#define DM 128
#define DI 512
#define DS 256
#define NH 16
#define HD 32
#define CONVD 1024
#define DIP 1552
#define NCH 800      // number of chunks
#define NCH2 400     // chunks per half
#define KSL 64       // K-slices for k_carry
#define CPS 7        // chunks per K-slice (ceil(400/64))
#define EPSV 1e-5f

typedef __attribute__((ext_vector_type(8))) short bf16x8;
typedef __attribute__((ext_vector_type(8))) unsigned short us8;
typedef __attribute__((ext_vector_type(4))) unsigned short us4;
typedef __attribute__((ext_vector_type(4))) float f32x4;
#define MFMA16(a,b,c) __builtin_amdgcn_mfma_f32_16x16x32_bf16(a,b,c,0,0,0)

__device__ __forceinline__ float b2f(unsigned short u){
  union{unsigned int i; float f;} v; v.i = ((unsigned int)u) << 16; return v.f;
}
__device__ __forceinline__ unsigned short f2b(float f){
  union{unsigned int i; float f;} v; v.f = f;
  unsigned int r = v.i + 0x7fffu + ((v.i >> 16) & 1u);
  return (unsigned short)(r >> 16);
}

// ---------------------------------------------------------------- K0: coef
__global__ void k_coef(const float* __restrict__ opw, const float* __restrict__ nw,
                       float* __restrict__ coef){
  int i = blockIdx.x * blockDim.x + threadIdx.x;
  if (i >= DI) return;
  float s = 0.f;
  for (int j = 0; j < DM; ++j) s += opw[j * DI + i];
  coef[i] = (s / (float)DM) * nw[i];
}

// ---------------------------------------------------------------- K0b: rank-4 table q[j] = (w.fw0, w.fw1, w.fw2, w.fb)
__global__ __launch_bounds__(256) void k_qtab(const float* __restrict__ ipw,
    const float* __restrict__ fw, const float* __restrict__ fb, float* __restrict__ q){
  int j = blockIdx.x * 256 + threadIdx.x;
  if (j >= DIP) return;
  const float* wr = ipw + (size_t)j * DM;
  float s0 = 0.f, s1 = 0.f, s2 = 0.f, sb = 0.f;
  for (int k = 0; k < DM; ++k){
    float w = wr[k];
    s0 += w * fw[k*3+0]; s1 += w * fw[k*3+1]; s2 += w * fw[k*3+2]; sb += w * fb[k];
  }
  reinterpret_cast<float4*>(q)[j] = make_float4(s0, s1, s2, sb);
}

// ---------------------------------------------------------------- helpers
__device__ __forceinline__ void xrow(const float* __restrict__ x, int l, float* o){
  int i, j;
  if (l < HW){ i = l / W_; j = l % W_; }
  else { int l2 = l - HW; i = (H_ - 1) - l2 / W_; j = (W_ - 1) - l2 % W_; }
  int p = i * W_ + j;
  o[0] = x[p]; o[1] = x[HW + p]; o[2] = x[2*HW + p];
}

// ---------------------------------------------------------------- K2: fused fc0 + in_proj + conv + silu + dt (rank-4)
// PROVEN FORM (r6/r8/r9: 87-99us, VGPR 92). DO NOT restructure: any reshaping
// of this body doubles live registers (156 VGPR, r7/r10) and costs ~50%.
__global__ __launch_bounds__(256) void k_fused(const float* __restrict__ x,
    const float* __restrict__ q, const float* __restrict__ cw, const float* __restrict__ cb,
    const float* __restrict__ dt_bias,
    unsigned short* __restrict__ g, unsigned short* __restrict__ xbc, float* __restrict__ dtb){
  int r0 = blockIdx.x * 32;          // 1600 blocks, 32 rows each
  int tid = threadIdx.x;
  // --- xBC: conv + silu. 8 l4-groups x 128 ch-slots
  {
    int c8 = tid & 127, lg = tid >> 7;
    const float4* qv8 = reinterpret_cast<const float4*>(q) + DI + c8 * 8;
    const float4* wv8 = reinterpret_cast<const float4*>(cw) + c8 * 8;
    const float4* cb2 = reinterpret_cast<const float4*>(cb) + c8 * 2;
    float4 bias0 = cb2[0], bias1 = cb2[1];
    float biasv[8] = {bias0.x,bias0.y,bias0.z,bias0.w,bias1.x,bias1.y,bias1.z,bias1.w};
    for (int it = 0; it < 4; ++it){
      int lbase = r0 + (it * 2 + lg) * 4;       // output rows lbase..lbase+3
      float xv[7][3], vf[7];
      #pragma unroll
      for (int k = 0; k < 7; ++k){
        int l = lbase - 3 + k;
        if (l >= 0){ xrow(x, l, xv[k]); vf[k] = 1.f; }
        else { xv[k][0] = xv[k][1] = xv[k][2] = 0.f; vf[k] = 0.f; }
      }
      unsigned int ow[4][4];
      #pragma unroll
      for (int e = 0; e < 8; ++e){
        float4 qv = qv8[e];
        float raw[7];
        #pragma unroll
        for (int k = 0; k < 7; ++k)
          raw[k] = vf[k]*qv.w + xv[k][0]*qv.x + xv[k][1]*qv.y + xv[k][2]*qv.z;
        float4 wv = wv8[e];
        float bias = biasv[e];
        #pragma unroll
        for (int rr = 0; rr < 4; ++rr){
          float acc = bias + raw[rr]*wv.x + raw[rr+1]*wv.y + raw[rr+2]*wv.z + raw[rr+3]*wv.w;
          float s = acc / (1.f + __expf(-acc));
          unsigned int b = f2b(s);
          if (e & 1) ow[rr][e >> 1] |= b << 16;
          else       ow[rr][e >> 1] = b;
        }
      }
      #pragma unroll
      for (int rr = 0; rr < 4; ++rr){
        uint4 o; o.x = ow[rr][0]; o.y = ow[rr][1]; o.z = ow[rr][2]; o.w = ow[rr][3];
        *reinterpret_cast<uint4*>(xbc + (size_t)(lbase + rr) * CONVD + c8 * 8) = o;
      }
    }
  }
  // --- z gate: silu, second half only
  if (r0 >= HW){
    int c8g = tid & 63;
    const float4* qv8 = reinterpret_cast<const float4*>(q) + c8g * 8;
    for (int it = 0; it < 8; ++it){
      int row = it * 4 + (tid >> 6);
      int l = r0 + row;
      float xv[3]; xrow(x, l, xv);
      unsigned int ow[4];
      #pragma unroll
      for (int e = 0; e < 8; ++e){
        float4 qv = qv8[e];
        float raw = qv.w + xv[0]*qv.x + xv[1]*qv.y + xv[2]*qv.z;
        float s = raw / (1.f + __expf(-raw));
        unsigned int b = f2b(s);
        if (e & 1) ow[e >> 1] |= b << 16;
        else       ow[e >> 1] = b;
      }
      uint4 o; o.x = ow[0]; o.y = ow[1]; o.z = ow[2]; o.w = ow[3];
      *reinterpret_cast<uint4*>(g + (size_t)(l - HW) * DI + c8g * 8) = o;
    }
  }
  // --- dt: softplus, f32. 32 rows x 16 h, 2 per thread
  {
    int row = tid >> 3, h2 = (tid & 7) * 2;
    int l = r0 + row;
    float xv[3]; xrow(x, l, xv);
    #pragma unroll
    for (int e = 0; e < 2; ++e){
      int h = h2 + e;
      float4 qv = reinterpret_cast<const float4*>(q)[DI + CONVD + h];
      float raw = qv.w + xv[0]*qv.x + xv[1]*qv.y + xv[2]*qv.z + dt_bias[h];
      float sp = (raw > 20.f) ? raw : log1pf(__expf(raw));
      dtb[(size_t)l * NH + h] = sp;
    }
  }
}

// ---------------------------------------------------------------- K3a: per-chunk sums of dt*A (first half)
__global__ void k_csum(const float* __restrict__ dtb, const float* __restrict__ A_log,
                       float* __restrict__ Scs){
  int idx = blockIdx.x * 256 + threadIdx.x;   // 6400 = 400 c x 16 h
  if (idx >= NCH2 * NH) return;
  int c = idx >> 4, h = idx & 15;
  float Ah = -__expf(A_log[h]);
  float s = 0.f;
  const float* p = dtb + (size_t)c * 64 * NH + h;
  for (int t = 0; t < 64; ++t) s += p[t * NH];
  Scs[idx] = s * Ah;
}

// ---------------------------------------------------------------- K3b: exclusive chunk prefix + total (first half)
__global__ __launch_bounds__(256) void k_cpre(const float* __restrict__ Scs,
    float* __restrict__ chunkpre, float* __restrict__ Ttot){
  __shared__ float segs[256];   // [seg][h]
  int tid = threadIdx.x;
  int h = tid & 15, seg = tid >> 4;
  int c0 = seg * 25;
  float v[25];
  float s = 0.f;
  #pragma unroll
  for (int j = 0; j < 25; ++j){ v[j] = Scs[(c0 + j) * NH + h]; s += v[j]; }
  segs[seg * 16 + h] = s;
  __syncthreads();
  float excl = 0.f;
  for (int s2 = 0; s2 < seg; ++s2) excl += segs[s2 * 16 + h];
  float run = excl;
  #pragma unroll
  for (int j = 0; j < 25; ++j){ chunkpre[(c0 + j) * NH + h] = run; run += v[j]; }
  if (seg == 15) Ttot[h] = run;
}

// ---------------------------------------------------------------- K3c: first-half carry, 4 heads per block
__global__ __launch_bounds__(256) void k_carry(const unsigned short* __restrict__ xbc,
    const float* __restrict__ dtb, const float* __restrict__ A_log,
    const float* __restrict__ chunkpre, const float* __restrict__ Ttot,
    float* __restrict__ part){
  __shared__ char U[50176];      // Bs 32KB + xwT4 16KB + wcs 1KB
  unsigned short* Bs = (unsigned short*)U;
  char* xwT4 = U + 32768;        // [4][32][64] bf16 swizzled
  float* wcs = (float*)(U + 49152);   // [4][64]
  int ks = blockIdx.x >> 2, hg = blockIdx.x & 3;
  int hbase = hg * 4;
  int tid = threadIdx.x, lane = tid & 63, wv = tid >> 6;
  int kg = lane >> 4, l15 = lane & 15;
  int c0 = ks * CPS, cend = min(c0 + CPS, NCH2);
  float Ahw = -__expf(A_log[hbase + wv]);     // wave-uniform
  float Ttw = Ttot[hbase + wv];
  f32x4 sacc[4][2][4];
  #pragma unroll
  for (int hh = 0; hh < 4; ++hh)
    #pragma unroll
    for (int mt = 0; mt < 2; ++mt)
      #pragma unroll
      for (int nt = 0; nt < 4; ++nt) sacc[hh][mt][nt] = (f32x4){0.f,0.f,0.f,0.f};
  for (int c = c0; c < cend; ++c){
    int l0 = c * 64;
    __syncthreads();                       // prev chunk's LDS reads done
    #pragma unroll
    for (int it = 0; it < 8; ++it){
      int r = (tid >> 5) + 8 * it, c8 = tid & 31;
      uint4 v = *reinterpret_cast<const uint4*>(xbc + (size_t)(l0 + r) * CONVD + DI + c8 * 8);
      *reinterpret_cast<uint4*>((char*)Bs + ((r * 512 + c8 * 16) ^ ((r & 7) << 4))) = v;
    }
    {                                      // per-wave 64-lane scan for its own head
      float d = dtb[(size_t)(l0 + lane) * NH + hbase + wv] * Ahw;
      #pragma unroll
      for (int off = 1; off < 64; off <<= 1){
        float o = __shfl_up(d, off, 64);
        if (lane >= off) d += o;
      }
      wcs[wv * 64 + lane] = __expf(Ttw - chunkpre[c * NH + hbase + wv] - d);
    }
    __syncthreads();                       // Bs + wcs ready
    bf16x8 bst[8];
    #pragma unroll
    for (int nt = 0; nt < 4; ++nt)
      #pragma unroll
      for (int s = 0; s < 2; ++s){
        int n = wv * 64 + nt * 16 + l15;
        int tb = s * 32 + kg * 8;
        bf16x8 f;
        #pragma unroll
        for (int e = 0; e < 8; ++e){
          int t = tb + e;
          f[e] = *reinterpret_cast<const short*>((char*)Bs + ((t * 512 + n * 2) ^ ((t & 7) << 4)));
        }
        bst[nt * 2 + s] = f;
      }
    #pragma unroll
    for (int hh = 0; hh < 4; ++hh){
      int t = lane, pb = wv;
      float w = wcs[hh * 64 + t] * dtb[(size_t)(l0 + t) * NH + hbase + hh];
      us8 x8 = *reinterpret_cast<const us8*>(xbc + (size_t)(l0 + t) * CONVD + (hbase + hh) * HD + pb * 8);
      #pragma unroll
      for (int e = 0; e < 8; ++e){
        int pp = pb * 8 + e;
        *reinterpret_cast<unsigned short*>(xwT4 + hh * 4096 + ((pp * 128 + t * 2) ^ ((pp & 7) << 4))) = f2b(b2f(x8[e]) * w);
      }
    }
    __syncthreads();                       // xwT ready
    #pragma unroll
    for (int s = 0; s < 2; ++s)
      #pragma unroll
      for (int hh = 0; hh < 4; ++hh)
        #pragma unroll
        for (int mt = 0; mt < 2; ++mt){
          int pr = mt * 16 + l15;
          bf16x8 a = *reinterpret_cast<const bf16x8*>(xwT4 + hh * 4096 + ((pr * 128 + (s*32 + kg*8) * 2) ^ ((pr & 7) << 4)));
          #pragma unroll
          for (int nt = 0; nt < 4; ++nt) sacc[hh][mt][nt] = MFMA16(a, bst[nt*2 + s], sacc[hh][mt][nt]);
        }
  }
  #pragma unroll
  for (int hh = 0; hh < 4; ++hh){
    float* pb2 = part + ((size_t)(ks * NH + hbase + hh)) * HD * DS;
    #pragma unroll
    for (int mt = 0; mt < 2; ++mt)
      #pragma unroll
      for (int nt = 0; nt < 4; ++nt)
        #pragma unroll
        for (int r = 0; r < 4; ++r)
          pb2[(mt * 16 + kg * 4 + r) * DS + wv * 64 + nt * 16 + l15] = sacc[hh][mt][nt][r];
  }
}

// ---------------------------------------------------------------- K3d: reduce K-slice partials -> carry
__global__ __launch_bounds__(256) void k_carryred(const float* __restrict__ part,
                                                  float* __restrict__ carry){
  int idx = blockIdx.x * 256 + threadIdx.x;  // 131072
  float s = 0.f;
  #pragma unroll 8
  for (int ks = 0; ks < KSL; ++ks) s += part[(size_t)ks * 131072 + idx];
  carry[idx] = s;
}

// ---------------------------------------------------------------- K4: per-chunk SSD core (second half), 16 heads/block
__global__ __launch_bounds__(256) void k_chunk(const unsigned short* __restrict__ xbc,
    const float* __restrict__ dtb, const float* __restrict__ A_log,
    unsigned short* __restrict__ states, float* __restrict__ atot,
    float* __restrict__ ecs, unsigned short* __restrict__ ydiag){
  __shared__ char U[65536];
  __shared__ float dts[1024];        // [t*16+h]
  __shared__ float Acs[1024];        // [h*64+t]
  unsigned short* Bs = (unsigned short*)U;
  unsigned short* Cs = (unsigned short*)(U + 32768);
  char* Mb  = U;                                   // [64][64] bf16 swizzled (8KB)
  char* xdT = U + 8192;                            // [32][64] bf16 swizzled (4KB)
  char* xwT = U + 12288;                           // [32][64] bf16 swizzled (4KB)
  unsigned short* stageS = (unsigned short*)(U + 16384);   // [32][264] bf16
  unsigned short* stageY = (unsigned short*)(U + 33280);   // [64][40] bf16
  int cl = blockIdx.x;
  int c = NCH2 + cl, l0 = c * 64;
  int tid = threadIdx.x, lane = tid & 63, wv = tid >> 6;
  int kg = lane >> 4, l15 = lane & 15;

  for (int i = tid; i < 1024; i += 256) dts[i] = dtb[(size_t)l0 * NH + i];
  #pragma unroll
  for (int it = 0; it < 8; ++it){
    int r = (tid >> 5) + 8 * it, c8 = tid & 31;
    uint4 v = *reinterpret_cast<const uint4*>(xbc + (size_t)(l0 + r) * CONVD + DI + c8 * 8);
    *reinterpret_cast<uint4*>((char*)Bs + ((r * 512 + c8 * 16) ^ ((r & 7) << 4))) = v;
    uint4 v2 = *reinterpret_cast<const uint4*>(xbc + (size_t)(l0 + r) * CONVD + DI + DS + c8 * 8);
    *reinterpret_cast<uint4*>((char*)Cs + ((r * 512 + c8 * 16) ^ ((r & 7) << 4))) = v2;
  }
  __syncthreads();
  if (tid < 16){
    int h = tid; float Ah = -__expf(A_log[h]); float s = 0.f;
    for (int t = 0; t < 64; ++t){ s += dts[t*16 + h] * Ah; Acs[h*64 + t] = s; }
    atot[c * NH + h] = __expf(s);
  }
  bf16x8 bst[8];     // [nt*2 + s]
  #pragma unroll
  for (int nt = 0; nt < 4; ++nt)
    #pragma unroll
    for (int s = 0; s < 2; ++s){
      int n = wv * 64 + nt * 16 + l15;
      int tb = s * 32 + kg * 8;
      bf16x8 f;
      #pragma unroll
      for (int e = 0; e < 8; ++e){
        int t = tb + e;
        f[e] = *reinterpret_cast<const short*>((char*)Bs + ((t * 512 + n * 2) ^ ((t & 7) << 4)));
      }
      bst[nt * 2 + s] = f;
    }
  f32x4 Gacc[4];
  {
    #pragma unroll
    for (int st = 0; st < 4; ++st) Gacc[st] = (f32x4){0.f,0.f,0.f,0.f};
    int trow = wv * 16 + l15;
    for (int ks = 0; ks < 8; ++ks){
      bf16x8 a = *reinterpret_cast<const bf16x8*>((char*)Cs + ((trow * 512 + (ks*32 + kg*8) * 2) ^ ((trow & 7) << 4)));
      #pragma unroll
      for (int st = 0; st < 4; ++st){
        int srow = st * 16 + l15;
        bf16x8 b = *reinterpret_cast<const bf16x8*>((char*)Bs + ((srow * 512 + (ks*32 + kg*8) * 2) ^ ((srow & 7) << 4)));
        Gacc[st] = MFMA16(a, b, Gacc[st]);
      }
    }
  }
  __syncthreads();     // Bs/Cs dead; Acs ready
  for (int h = 0; h < NH; ++h){
    float alast = Acs[h*64 + 63];
    {
      int t = tid & 63, pb = tid >> 6;
      float dtv = dts[t*16 + h];
      float dec = __expf(alast - Acs[h*64 + t]);
      us8 x8 = *reinterpret_cast<const us8*>(xbc + (size_t)(l0 + t) * CONVD + h * HD + pb * 8);
      #pragma unroll
      for (int e = 0; e < 8; ++e){
        int pp = pb * 8 + e;
        float v = b2f(x8[e]) * dtv;
        *reinterpret_cast<unsigned short*>(xdT + ((pp * 128 + t * 2) ^ ((pp & 7) << 4))) = f2b(v);
        *reinterpret_cast<unsigned short*>(xwT + ((pp * 128 + t * 2) ^ ((pp & 7) << 4))) = f2b(v * dec);
      }
    }
    {
      #pragma unroll
      for (int st = 0; st < 4; ++st)
        #pragma unroll
        for (int r = 0; r < 4; ++r){
          int t = wv * 16 + kg * 4 + r, s2 = st * 16 + l15;
          float m = (s2 <= t) ? Gacc[st][r] * __expf(Acs[h*64 + t] - Acs[h*64 + s2]) : 0.f;
          *reinterpret_cast<unsigned short*>(Mb + ((t * 128 + s2 * 2) ^ ((t & 7) << 4))) = f2b(m);
        }
      if (tid < 64) ecs[((size_t)cl * NH + h) * 64 + tid] = __expf(Acs[h*64 + tid]);
    }
    __syncthreads();
    {
      f32x4 sacc[2][4];
      #pragma unroll
      for (int mt = 0; mt < 2; ++mt)
        #pragma unroll
        for (int nt = 0; nt < 4; ++nt) sacc[mt][nt] = (f32x4){0.f,0.f,0.f,0.f};
      #pragma unroll
      for (int s = 0; s < 2; ++s)
        #pragma unroll
        for (int mt = 0; mt < 2; ++mt){
          int pr = mt * 16 + l15;
          bf16x8 a = *reinterpret_cast<const bf16x8*>(xwT + ((pr * 128 + (s*32 + kg*8) * 2) ^ ((pr & 7) << 4)));
          #pragma unroll
          for (int nt = 0; nt < 4; ++nt) sacc[mt][nt] = MFMA16(a, bst[nt*2 + s], sacc[mt][nt]);
        }
      #pragma unroll
      for (int mt = 0; mt < 2; ++mt)
        #pragma unroll
        for (int nt = 0; nt < 4; ++nt)
          #pragma unroll
          for (int r = 0; r < 4; ++r){
            int pp = mt * 16 + kg * 4 + r, n = wv * 64 + nt * 16 + l15;
            stageS[pp * 264 + n] = f2b(sacc[mt][nt][r]);
          }
    }
    {
      f32x4 yacc[2];
      yacc[0] = (f32x4){0.f,0.f,0.f,0.f}; yacc[1] = (f32x4){0.f,0.f,0.f,0.f};
      int trow = wv * 16 + l15;
      #pragma unroll
      for (int s = 0; s < 2; ++s){
        bf16x8 a = *reinterpret_cast<const bf16x8*>(Mb + ((trow * 128 + (s*32 + kg*8) * 2) ^ ((trow & 7) << 4)));
        #pragma unroll
        for (int pt = 0; pt < 2; ++pt){
          int pr = pt * 16 + l15;
          bf16x8 b = *reinterpret_cast<const bf16x8*>(xdT + ((pr * 128 + (s*32 + kg*8) * 2) ^ ((pr & 7) << 4)));
          yacc[pt] = MFMA16(a, b, yacc[pt]);
        }
      }
      #pragma unroll
      for (int pt = 0; pt < 2; ++pt)
        #pragma unroll
        for (int r = 0; r < 4; ++r){
          int t = wv * 16 + kg * 4 + r, pp = pt * 16 + l15;
          stageY[t * 40 + pp] = f2b(yacc[pt][r]);
        }
    }
    __syncthreads();
    {
      int row = tid >> 3, seg = tid & 7;
      const unsigned short* sp = stageS + row * 264 + seg * 32;
      unsigned short* gp = states + (((size_t)cl * NH + h) * HD + row) * DS + seg * 32;
      #pragma unroll
      for (int k = 0; k < 4; ++k)
        *reinterpret_cast<uint4*>(gp + k * 8) = *reinterpret_cast<const uint4*>(sp + k * 8);
      {
        int rw = tid >> 2, quad = tid & 3;
        *reinterpret_cast<uint4*>(ydiag + (size_t)(l0 - HW + rw) * DI + h * HD + quad * 8)
          = *reinterpret_cast<const uint4*>(stageY + rw * 40 + quad * 8);
      }
    }
    __syncthreads();
  }
}

// ---------------------------------------------------------------- K5b: in-place prefix over second-half states
__global__ __launch_bounds__(256) void k_scan2(unsigned short* __restrict__ states,
    const float* __restrict__ atot, const float* __restrict__ carry){
  __shared__ float sat[NCH2];
  int idx = blockIdx.x * 256 + threadIdx.x;
  int h = idx >> 13;
  for (int c = threadIdx.x; c < NCH2; c += 256) sat[c] = atot[(NCH2 + c) * NH + h];
  __syncthreads();
  float cr = carry[idx];
  unsigned short* p = states + idx;
  for (int c = 0; c < NCH2; ++c){
    float s = b2f(*p);
    *p = f2b(cr);
    cr = sat[c] * cr + s;
    p += 131072;
  }
}

// ---------------------------------------------------------------- K6: Y_off + skip + gate + sumsq (MFMA, LDS-staged)
__global__ __launch_bounds__(256) void k_yoff(const unsigned short* __restrict__ xbc,
    const unsigned short* __restrict__ states, const float* __restrict__ ecs,
    const float* __restrict__ Dv, unsigned short* __restrict__ y,
    const unsigned short* __restrict__ g, float* __restrict__ rms){
  __shared__ unsigned short stage[64 * 520];
  __shared__ float ecs_s[1024];
  int c2 = blockIdx.x;
  int c = c2 + NCH2, l0 = c * 64;
  int tid = threadIdx.x, lane = tid & 63, wv = tid >> 6;
  int kg = lane >> 4, l15 = lane & 15;
  for (int i = tid; i < 1024; i += 256) ecs_s[i] = ecs[(size_t)c2 * 1024 + i];
  bf16x8 aC[8];
  int trow = wv * 16 + l15;
  #pragma unroll
  for (int ks = 0; ks < 8; ++ks)
    aC[ks] = *reinterpret_cast<const bf16x8*>(xbc + (size_t)(l0 + trow) * CONVD + DI + DS + ks * 32 + kg * 8);
  __syncthreads();
  for (int h = 0; h < NH; ++h){
    f32x4 acc[2];
    acc[0] = (f32x4){0.f,0.f,0.f,0.f}; acc[1] = (f32x4){0.f,0.f,0.f,0.f};
    const unsigned short* sb = states + ((size_t)c2 * NH + h) * HD * DS;
    #pragma unroll
    for (int ks = 0; ks < 8; ++ks)
      #pragma unroll
      for (int pt = 0; pt < 2; ++pt){
        bf16x8 b = *reinterpret_cast<const bf16x8*>(sb + (pt * 16 + l15) * DS + ks * 32 + kg * 8);
        acc[pt] = MFMA16(aC[ks], b, acc[pt]);
      }
    float Dh = Dv[h];
    #pragma unroll
    for (int pt = 0; pt < 2; ++pt)
      #pragma unroll
      for (int r = 0; r < 4; ++r){
        int t = wv * 16 + kg * 4 + r, pp = pt * 16 + l15;
        float xh = b2f(xbc[(size_t)(l0 + t) * CONVD + h * HD + pp]);
        stage[t * 520 + h * HD + pp] = f2b(ecs_s[h*64 + t] * acc[pt][r] + Dh * xh);
      }
  }
  __syncthreads();
  int row = tid >> 2, quad = tid & 3;
  const unsigned short* sr = stage + row * 520 + quad * 128;
  size_t obase = (size_t)(c2 * 64 + row) * DI + quad * 128;
  float ss = 0.f;
  #pragma unroll
  for (int k = 0; k < 16; ++k){
    uint4 sv = *reinterpret_cast<const uint4*>(sr + k * 8);
    uint4 yv = *reinterpret_cast<const uint4*>(y + obase + k * 8);
    uint4 gv = *reinterpret_cast<const uint4*>(g + obase + k * 8);
    unsigned int ow[4];
    const unsigned int* svp = (const unsigned int*)&sv;
    const unsigned int* yvp = (const unsigned int*)&yv;
    const unsigned int* gvp = (const unsigned int*)&gv;
    #pragma unroll
    for (int e = 0; e < 4; ++e){
      float v0 = b2f((unsigned short)(svp[e] & 0xffff)) + b2f((unsigned short)(yvp[e] & 0xffff));
      float v1 = b2f((unsigned short)(svp[e] >> 16)) + b2f((unsigned short)(yvp[e] >> 16));
      float y0 = v0 * b2f((unsigned short)(gvp[e] & 0xffff));
      float y1 = v1 * b2f((unsigned short)(gvp[e] >> 16));
      ss += y0 * y0 + y1 * y1;
      ow[e] = (unsigned int)f2b(y0) | ((unsigned int)f2b(y1) << 16);
    }
    uint4 o; o.x = ow[0]; o.y = ow[1]; o.z = ow[2]; o.w = ow[3];
    *reinterpret_cast<uint4*>(y + obase + k * 8) = o;
  }
  ss += __shfl_xor(ss, 1, 64);
  ss += __shfl_xor(ss, 2, 64);
  if (quad == 0) rms[c2 * 64 + row] = rsqrtf(ss / (float)DI + EPSV);
}

// ---------------------------------------------------------------- K7: half[l] = rms * (y . coef)
__global__ __launch_bounds__(256) void k_half(const unsigned short* __restrict__ yg,
    const float* __restrict__ rms, const float* __restrict__ coef,
    float* __restrict__ half_out){
  int wave = threadIdx.x >> 6, lane = threadIdx.x & 63;
  int row = blockIdx.x * 4 + wave;
  if (row >= HW) return;
  const unsigned short* yr = yg + (size_t)row * DI;
  float acc = 0.f;
  for (int i = lane; i < DI; i += 64) acc += b2f(yr[i]) * coef[i];
  #pragma unroll
  for (int off = 32; off; off >>= 1) acc += __shfl_down(acc, off, 64);
  if (lane == 0) half_out[row] = acc * rms[row];
}

// ---------------------------------------------------------------- K8: final fc1
__global__ __launch_bounds__(256) void k_fc1(const float* __restrict__ half_in,
    const float* __restrict__ w, const float* __restrict__ b, float* __restrict__ out){
  int k = blockIdx.x;
  const float* wr = w + (size_t)k * HW;
  float acc = 0.f;
  for (int i = threadIdx.x; i < HW; i += 256) acc += half_in[i] * wr[i];
  __shared__ float red[256];
  red[threadIdx.x] = acc;
  __syncthreads();
  for (int s = 128; s; s >>= 1){
    if (threadIdx.x < s) red[threadIdx.x] += red[threadIdx.x + s];
    __syncthreads();
  }
  if (threadIdx.x == 0) out[k] = red[0] + b[k];
}

// ---------------------------------------------------------------- launch
extern "C" void kernel_launch(void* const* d_in, const int* in_sizes, int n_in,
                              void* d_out, int out_size, void* d_ws, size_t ws_size,
                              hipStream_t stream){
  const float* x      = (const float*)d_in[0];
  const float* fc0_w  = (const float*)d_in[1];
  const float* fc0_b  = (const float*)d_in[2];
  const float* ipw    = (const float*)d_in[3];
  const float* conv_w = (const float*)d_in[4];
  const float* conv_b = (const float*)d_in[5];
  const float* dt_bias= (const float*)d_in[6];
  const float* A_log  = (const float*)d_in[7];
  const float* Dv     = (const float*)d_in[8];
  const float* norm_w = (const float*)d_in[9];
  const float* opw    = (const float*)d_in[10];
  const float* fc1_w  = (const float*)d_in[11];
  const float* fc1_b  = (const float*)d_in[12];
  float* out = (float*)d_out;

  char* ws = (char*)d_ws;
  size_t off = 0;
  float* dtb          = (float*)(ws + off);           off += (size_t)L_ * NH * 4;          // 3.3 MB
  unsigned short* stx = (unsigned short*)(ws + off);  off += (size_t)L_ * CONVD * 2;       // 104.9 MB (carry partials, then 400-chunk states)
  unsigned short* xbc = (unsigned short*)(ws + off);  off += (size_t)L_ * CONVD * 2;       // 104.9 MB
  unsigned short* g   = (unsigned short*)(ws + off);  off += (size_t)HW * DI * 2;          // 26.2 MB
  unsigned short* yd  = (unsigned short*)(ws + off);  off += (size_t)HW * DI * 2;          // 26.2 MB
  float* atot         = (float*)(ws + off);           off += (size_t)NCH * NH * 4;
  float* ecs          = (float*)(ws + off);           off += (size_t)NCH2 * NH * 64 * 4;
  float* rms          = (float*)(ws + off);           off += (size_t)HW * 4;
  float* half_buf     = (float*)(ws + off);           off += (size_t)HW * 4;
  float* coef         = (float*)(ws + off);           off += (size_t)DI * 4;
  float* carry        = (float*)(ws + off);           off += (size_t)131072 * 4;
  float* qtab         = (float*)(ws + off);           off += (size_t)DIP * 4 * 4;
  float* Scs          = (float*)(ws + off);           off += (size_t)NCH2 * NH * 4;
  float* chunkpre     = (float*)(ws + off);           off += (size_t)NCH2 * NH * 4;
  float* Ttot         = (float*)(ws + off);           off += (size_t)NH * 4;
  float* part         = (float*)stx;                  // alias: dead before k_chunk writes stx

  if (ws_size < off) return;   // diagnostic guard

  k_coef    <<<2, 256, 0, stream>>>(opw, norm_w, coef);
  k_qtab    <<<(DIP + 255) / 256, 256, 0, stream>>>(ipw, fc0_w, fc0_b, qtab);
  k_fused   <<<L_ / 32, 256, 0, stream>>>(x, qtab, conv_w, conv_b, dt_bias, g, xbc, dtb);
  k_csum    <<<25, 256, 0, stream>>>(dtb, A_log, Scs);
  k_cpre    <<<1, 256, 0, stream>>>(Scs, chunkpre, Ttot);
  k_carry   <<<KSL * 4, 256, 0, stream>>>(xbc, dtb, A_log, chunkpre, Ttot, part);
  k_carryred<<<512, 256, 0, stream>>>(part, carry);
  k_chunk   <<<NCH2, 256, 0, stream>>>(xbc, dtb, A_log, stx, atot, ecs, yd);
  k_scan2   <<<512, 256, 0, stream>>>(stx, atot, carry);
  k_yoff    <<<NCH2, 256, 0, stream>>>(xbc, stx, ecs, Dv, yd, g, rms);
  k_half    <<<HW / 4, 256, 0, stream>>>(yd, rms, coef, half_buf);
  k_fc1     <<<DM, 256, 0, stream>>>(half_buf, fc1_w, fc1_b, out);
}